// Round 6
// baseline (2246.801 us; speedup 1.0000x reference)
//
#include <hip/hip_runtime.h>
#include <math.h>

// Problem constants
#define BB      128
#define NNODES  1023
#define HD      256
#define LEAVES  512
#define IOU3    768     // 3*H
#define CAT2    512     // 2*H
#define LDCOMB  1280    // f(512) + iou(768)

typedef unsigned short ushort_t;
typedef __bf16 bf16x8 __attribute__((ext_vector_type(8)));
typedef float  f32x4  __attribute__((ext_vector_type(4)));

__device__ __forceinline__ float sigf(float x) { return 1.0f / (1.0f + expf(-x)); }

// split fp32 -> bf16 hi + bf16 lo (round-to-nearest-even, bit ops)
__device__ __forceinline__ void split_bf16(float x, ushort_t& h, ushort_t& l)
{
    unsigned u = __float_as_uint(x);
    unsigned r = u + 0x7fff + ((u >> 16) & 1);
    h = (ushort_t)(r >> 16);
    float fh = __uint_as_float((unsigned)h << 16);
    float d = x - fh;
    unsigned u2 = __float_as_uint(d);
    unsigned r2 = u2 + 0x7fff + ((u2 >> 16) & 1);
    l = (ushort_t)(r2 >> 16);
}

__device__ __forceinline__ float rh2(ushort_t h, ushort_t l)
{
    return __uint_as_float((unsigned)h << 16) + __uint_as_float((unsigned)l << 16);
}

// ---------------------------------------------------------------------------
// generic fp32 array -> hi/lo bf16 arrays (4 elements/thread)
// ---------------------------------------------------------------------------
__global__ void k_split4(const float* __restrict__ src, ushort_t* __restrict__ hi,
                         ushort_t* __restrict__ lo, int n4)
{
    int i = blockIdx.x * 256 + threadIdx.x;
    if (i >= n4) return;
    float4 v = ((const float4*)src)[i];
    ushort4 hv, lv;
    split_bf16(v.x, hv.x, lv.x);
    split_bf16(v.y, hv.y, lv.y);
    split_bf16(v.z, hv.z, lv.z);
    split_bf16(v.w, hv.w, lv.w);
    ((ushort4*)hi)[i] = hv;
    ((ushort4*)lo)[i] = lv;
}

// build Wcat = [Uf_W(512 rows) ; U_iou(768 rows)], K=512, as hi/lo bf16
__global__ void k_build_wcat(const float* __restrict__ Uf, const float* __restrict__ Ui,
                             ushort_t* __restrict__ hi, ushort_t* __restrict__ lo)
{
    int i = blockIdx.x * 256 + threadIdx.x;       // over 1280*128 float4s
    if (i >= 1280 * 128) return;
    int row = i >> 7, c4 = i & 127;
    const float* src = (row < 512) ? (Uf + (size_t)row * 512)
                                   : (Ui + (size_t)(row - 512) * 512);
    float4 v = ((const float4*)src)[c4];
    ushort4 hv, lv;
    split_bf16(v.x, hv.x, lv.x);
    split_bf16(v.y, hv.y, lv.y);
    split_bf16(v.z, hv.z, lv.z);
    split_bf16(v.w, hv.w, lv.w);
    ((ushort4*)hi)[i] = hv;
    ((ushort4*)lo)[i] = lv;
}

// ---------------------------------------------------------------------------
// MFMA split-bf16 GEMM:  C[m][n] = sum_k A[m][k]*W[n][k]  (fp32-accurate)
// Block 128x256, BK=32, 512 threads = 8 waves (2m x 4n), wave tile 64x64
// (16 ds_read_b128 -> 48 MFMA per K-step: MFMA-bound, not LDS-read-bound).
// Single 48KB LDS K-buffer + reg prefetch; 2 blocks/CU = 16 waves/CU.
// Slab swizzle: XCD-preserving (new bx % 8 == flat % 8).
// Round-3 lesson: never give an XCD a contiguous by-band.
// ---------------------------------------------------------------------------
#define BM 128
#define BN 256
#define BK 32

__global__ __launch_bounds__(512, 4)
void gemm_mfma(const ushort_t* __restrict__ Ahi, const ushort_t* __restrict__ Alo,
               const int* __restrict__ ids,
               int lognpar, unsigned sB, int sP, int m0, int K,
               const ushort_t* __restrict__ Bhi, const ushort_t* __restrict__ Blo,
               float* __restrict__ C, int ldc)
{
    __shared__ __align__(16) char lds[49152];
    const int tid = threadIdx.x;

    // slab-ordered, XCD-preserving block swizzle
    int bx = blockIdx.x, by = blockIdx.y;
    {
        const int gx = gridDim.x, gy = gridDim.y;
        if ((gx & 7) == 0) {
            int f = by * gx + bx;        // HW dispatch order (x fastest)
            int span = gy << 3;          // 8 * gy blocks per slab
            int s = f / span;
            int wv = f - s * span;
            bx = (s << 3) + (wv & 7);    // bx % 8 == f % 8 -> same XCD
            by = wv >> 3;
        }
    }

    // staging: slot = 16B = 8 bf16. A: 512 slots (1/thread); B: 1024 (2/thread)
    const int arow = tid >> 2, ako = tid & 3;
    unsigned aoff, boff[2];
    {
        int mg = m0 + bx * BM + arow;
        unsigned ab;
        if (ids) {
            ab = (unsigned)ids[mg] * (unsigned)K;
        } else {
            int b = mg >> lognpar;
            int p = mg & ((1 << lognpar) - 1);
            ab = (unsigned)b * sB + (unsigned)p * (unsigned)sP;
        }
        aoff = ab + ako * 8;
    }
    const int wofsA = arow * 64 + ((ako ^ ((arow >> 1) & 3)) << 4);
    int wofsB[2];
#pragma unroll
    for (int i = 0; i < 2; ++i) {
        int sl = tid + 512 * i;
        int brow = sl >> 2, bko = sl & 3;
        boff[i] = (unsigned)(by * BN + brow) * (unsigned)K + bko * 8;
        wofsB[i] = brow * 64 + ((bko ^ ((brow >> 1) & 3)) << 4);
    }

    uint4 rAh, rAl, rBh[2], rBl[2];
    auto LOADT = [&](int k0) {
        rAh = *(const uint4*)(Ahi + aoff + k0);
        rAl = *(const uint4*)(Alo + aoff + k0);
#pragma unroll
        for (int i = 0; i < 2; ++i) {
            rBh[i] = *(const uint4*)(Bhi + boff[i] + k0);
            rBl[i] = *(const uint4*)(Blo + boff[i] + k0);
        }
    };
    auto STORE = [&]() {
        *(uint4*)(lds +     0 + wofsA) = rAh;
        *(uint4*)(lds +  8192 + wofsA) = rAl;
#pragma unroll
        for (int i = 0; i < 2; ++i) {
            *(uint4*)(lds + 16384 + wofsB[i]) = rBh[i];
            *(uint4*)(lds + 32768 + wofsB[i]) = rBl[i];
        }
    };

    // fragment read addresses: 8 waves as 2(m) x 4(n); wave tile 64x64
    const int w = tid >> 6, lane = tid & 63;
    const int wm = w >> 2, wn = w & 3;
    const int rA0 = wm * 64 + (lane & 15);
    const int rB0 = wn * 64 + (lane & 15);
    const int ko = lane >> 4;
    const int rdA = rA0 * 64 + ((ko ^ ((rA0 >> 1) & 3)) << 4);
    const int rdB = rB0 * 64 + ((ko ^ ((rB0 >> 1) & 3)) << 4);

    f32x4 acc[4][4];
#pragma unroll
    for (int mi = 0; mi < 4; ++mi)
#pragma unroll
        for (int ni = 0; ni < 4; ++ni) acc[mi][ni] = (f32x4){0.f, 0.f, 0.f, 0.f};

    const int nt = K / BK;
    LOADT(0);
    STORE();
    __syncthreads();
    for (int t = 0; t < nt; ++t) {
        if (t + 1 < nt) LOADT((t + 1) * BK);   // prefetch next tile into regs
        bf16x8 ah[4], al[4], bh[4], bl[4];
#pragma unroll
        for (int f = 0; f < 4; ++f) {
            ah[f] = *(const bf16x8*)(lds +         rdA + f * 1024);
            al[f] = *(const bf16x8*)(lds +  8192 + rdA + f * 1024);
            bh[f] = *(const bf16x8*)(lds + 16384 + rdB + f * 1024);
            bl[f] = *(const bf16x8*)(lds + 32768 + rdB + f * 1024);
        }
        __builtin_amdgcn_s_setprio(1);
#pragma unroll
        for (int mi = 0; mi < 4; ++mi)
#pragma unroll
            for (int ni = 0; ni < 4; ++ni) {
                acc[mi][ni] = __builtin_amdgcn_mfma_f32_16x16x32_bf16(ah[mi], bh[ni], acc[mi][ni], 0, 0, 0);
                acc[mi][ni] = __builtin_amdgcn_mfma_f32_16x16x32_bf16(ah[mi], bl[ni], acc[mi][ni], 0, 0, 0);
                acc[mi][ni] = __builtin_amdgcn_mfma_f32_16x16x32_bf16(al[mi], bh[ni], acc[mi][ni], 0, 0, 0);
            }
        __builtin_amdgcn_s_setprio(0);
        __syncthreads();                        // all reads of K-buffer done
        if (t + 1 < nt) {
            STORE();                            // refill K-buffer from regs
            __syncthreads();                    // writes visible
        }
    }

    // ---- epilogue: per-wave repack through LDS -> 256B-contiguous stores ----
    // wave w uses lds[w*4352 .. +4352): 16 rows x 272B (64 floats + 4 pad)
    {
        char* patch = lds + w * 4352;
        const int cl = lane & 15, rg = lane >> 4;
        const int gcol0 = by * BN + wn * 64;
#pragma unroll
        for (int mi = 0; mi < 4; ++mi) {
#pragma unroll
            for (int ni = 0; ni < 4; ++ni)
#pragma unroll
                for (int r = 0; r < 4; ++r)
                    *(float*)(patch + (rg * 4 + r) * 272 + (ni * 16 + cl) * 4) = acc[mi][ni][r];
            int grow0 = bx * BM + wm * 64 + mi * 16;
#pragma unroll
            for (int it = 0; it < 4; ++it) {
                int lr = it * 4 + rg;
                f32x4 vv = *(const f32x4*)(patch + lr * 272 + cl * 16);
                *(f32x4*)(C + (size_t)(grow0 + lr) * ldc + gcol0 + cl * 4) = vv;
            }
        }
    }
}

// ---------------------------------------------------------------------------
// leaf id gather
// ---------------------------------------------------------------------------
__global__ void k_leaf_ids(const int* __restrict__ wordid, int* __restrict__ ids)
{
    int idx = blockIdx.x * 256 + threadIdx.x;   // 65536 total
    int b = idx >> 9, leaf = idx & 511;
    ids[idx] = wordid[b * NNODES + 511 + leaf];
}

// ---------------------------------------------------------------------------
// leaf apply: buf[m][768] (iou) -> h(hi/lo), c at node 511+leaf
// ---------------------------------------------------------------------------
__global__ void k_apply_leaf(const float* __restrict__ buf, const float* __restrict__ b_iou,
                             const float* __restrict__ c0,
                             ushort_t* __restrict__ hhi, ushort_t* __restrict__ hlo,
                             float* __restrict__ c, int m0)
{
    int idx = blockIdx.x * 256 + threadIdx.x;
    int m_l = idx >> 8, hh = idx & 255;
    int mg = m0 + m_l;
    int b = mg >> 9, leaf = mg & 511;
    int node = 511 + leaf;
    const float* br = buf + (size_t)m_l * IOU3;
    float iv = br[hh]        + b_iou[hh];
    float ov = br[256 + hh]  + b_iou[256 + hh];
    float uv = br[512 + hh]  + b_iou[512 + hh];
    size_t nb = ((size_t)b * NNODES + node) * HD + hh;
    float cn = sigf(iv) * tanhf(uv) + c0[nb];
    float hn = sigf(ov) * tanhf(cn);
    c[nb] = cn;
    split_bf16(hn, hhi[nb], hlo[nb]);
}

// ---------------------------------------------------------------------------
// level apply: buf[m][1280] = [f_l | f_r | i | o | u]
// ---------------------------------------------------------------------------
__global__ void k_apply_level(const float* __restrict__ buf, const float* __restrict__ b_iou,
                              const float* __restrict__ Uf_b,
                              ushort_t* __restrict__ hhi, ushort_t* __restrict__ hlo,
                              float* __restrict__ c,
                              int m0, int lognpar, int ps, int cs)
{
    int idx = blockIdx.x * 256 + threadIdx.x;
    int m_l = idx >> 8, hh = idx & 255;
    int mg = m0 + m_l;
    int b = mg >> lognpar;
    int p = mg & ((1 << lognpar) - 1);
    const float* br = buf + (size_t)m_l * LDCOMB;
    float fl = sigf(br[hh]        + Uf_b[hh]);
    float fr = sigf(br[256 + hh]  + Uf_b[256 + hh]);
    size_t cb = ((size_t)b * NNODES + cs + 2 * p) * HD + hh;
    float csum = fl * c[cb] + fr * c[cb + HD];
    float iv = br[512 + hh]  + b_iou[hh];
    float ov = br[768 + hh]  + b_iou[256 + hh];
    float uv = br[1024 + hh] + b_iou[512 + hh];
    float cn = sigf(iv) * tanhf(uv) + csum;
    float hn = sigf(ov) * tanhf(cn);
    size_t pb = ((size_t)b * NNODES + ps + p) * HD + hh;
    c[pb] = cn;
    split_bf16(hn, hhi[pb], hlo[pb]);
}

// ---------------------------------------------------------------------------
// v[b][k] = sum_g h[b][0][g] * Wmem[g][k]
// ---------------------------------------------------------------------------
__global__ void k_dec_v(const ushort_t* __restrict__ hhi, const ushort_t* __restrict__ hlo,
                        const float* __restrict__ Wmem, float* __restrict__ v)
{
    int b = blockIdx.x, k = threadIdx.x;
    __shared__ float dec[HD];
    size_t base = (size_t)b * NNODES * HD;
    dec[k] = rh2(hhi[base + k], hlo[base + k]);
    __syncthreads();
    float s = 0.f;
    for (int g = 0; g < HD; ++g) s = fmaf(dec[g], Wmem[g * HD + k], s);
    v[b * HD + k] = s;
}

// ---------------------------------------------------------------------------
// scores[b][n] = v_b . h[b][n]
// ---------------------------------------------------------------------------
__global__ void k_scores(const ushort_t* __restrict__ hhi, const ushort_t* __restrict__ hlo,
                         const float* __restrict__ v, float* __restrict__ scores)
{
    int b = blockIdx.x;
    int w = threadIdx.x >> 6, lane = threadIdx.x & 63;
    int n = blockIdx.y * 4 + w;
    if (n >= NNODES) return;
    size_t hb = ((size_t)b * NNODES + n) * HD;
    ushort4 ph = *(const ushort4*)(hhi + hb + lane * 4);
    ushort4 pl = *(const ushort4*)(hlo + hb + lane * 4);
    float4 vv = *(const float4*)(v + b * HD + lane * 4);
    float s = rh2(ph.x, pl.x) * vv.x + rh2(ph.y, pl.y) * vv.y +
              rh2(ph.z, pl.z) * vv.z + rh2(ph.w, pl.w) * vv.w;
#pragma unroll
    for (int o = 32; o; o >>= 1) s += __shfl_down(s, o);
    if (lane == 0) scores[(size_t)b * NNODES + n] = s;
}

// ---------------------------------------------------------------------------
// softmax over n (1023) per batch row
// ---------------------------------------------------------------------------
__global__ void k_softmax(const float* __restrict__ scores, float* __restrict__ attn)
{
    int b = blockIdx.x, t = threadIdx.x;
    __shared__ float red[4];
    float sv[4];
    float m = -INFINITY;
#pragma unroll
    for (int i = 0; i < 4; ++i) {
        int n = t + 256 * i;
        sv[i] = (n < NNODES) ? scores[(size_t)b * NNODES + n] : -INFINITY;
        m = fmaxf(m, sv[i]);
    }
#pragma unroll
    for (int o = 32; o; o >>= 1) m = fmaxf(m, __shfl_xor(m, o));
    int w = t >> 6, lane = t & 63;
    if (lane == 0) red[w] = m;
    __syncthreads();
    m = fmaxf(fmaxf(red[0], red[1]), fmaxf(red[2], red[3]));
    float s = 0.f;
#pragma unroll
    for (int i = 0; i < 4; ++i) {
        int n = t + 256 * i;
        sv[i] = (n < NNODES) ? expf(sv[i] - m) : 0.f;
        s += sv[i];
    }
#pragma unroll
    for (int o = 32; o; o >>= 1) s += __shfl_xor(s, o);
    __syncthreads();
    if (lane == 0) red[w] = s;
    __syncthreads();
    s = red[0] + red[1] + red[2] + red[3];
    float inv = 1.0f / s;
#pragma unroll
    for (int i = 0; i < 4; ++i) {
        int n = t + 256 * i;
        if (n < NNODES) attn[(size_t)b * NNODES + n] = sv[i] * inv;
    }
}

// ---------------------------------------------------------------------------
// context partials
// ---------------------------------------------------------------------------
__global__ void k_context(const ushort_t* __restrict__ hhi, const ushort_t* __restrict__ hlo,
                          const float* __restrict__ attn, float* __restrict__ partial)
{
    int b = blockIdx.x, ch = blockIdx.y, k = threadIdx.x;
    int n0 = ch * 128;
    int n1 = n0 + 128; if (n1 > NNODES) n1 = NNODES;
    float s = 0.f;
    for (int n = n0; n < n1; ++n) {
        size_t i = ((size_t)b * NNODES + n) * HD + k;
        s = fmaf(attn[(size_t)b * NNODES + n], rh2(hhi[i], hlo[i]), s);
    }
    partial[((size_t)b * 8 + ch) * HD + k] = s;
}

// ---------------------------------------------------------------------------
// final head
// ---------------------------------------------------------------------------
__global__ void k_final(const float* __restrict__ partial,
                        const float* __restrict__ wh_W, const float* __restrict__ wh_b,
                        const float* __restrict__ lin_W, const float* __restrict__ lin_b,
                        float* __restrict__ out)
{
    int b = blockIdx.x, j = threadIdx.x;
    __shared__ float ctx[HD];
    __shared__ float hid[HD];
    float s = 0.f;
#pragma unroll
    for (int ch = 0; ch < 8; ++ch) s += partial[((size_t)b * 8 + ch) * HD + j];
    ctx[j] = s;
    __syncthreads();
    float a = wh_b[j];
    for (int k = 0; k < HD; ++k) a = fmaf(ctx[k], wh_W[j * HD + k], a);
    hid[j] = fmaxf(a, 0.f);
    __syncthreads();
    if (j < 10) {
        float o = lin_b[j];
        for (int k = 0; k < HD; ++k) o = fmaf(hid[k], lin_W[j * HD + k], o);
        out[b * 10 + j] = o;
    }
}

// ---------------------------------------------------------------------------
extern "C" void kernel_launch(void* const* d_in, const int* in_sizes, int n_in,
                              void* d_out, int out_size, void* d_ws, size_t ws_size,
                              hipStream_t stream)
{
    const int*   wordid = (const int*)d_in[0];
    const float* c0     = (const float*)d_in[2];
    const float* emb    = (const float*)d_in[3];
    const float* W_iou  = (const float*)d_in[4];
    const float* U_iou  = (const float*)d_in[5];
    const float* b_iou  = (const float*)d_in[6];
    const float* Uf_W   = (const float*)d_in[7];
    const float* Uf_b   = (const float*)d_in[8];
    const float* Wmem   = (const float*)d_in[9];
    const float* wh_W   = (const float*)d_in[10];
    const float* wh_b   = (const float*)d_in[11];
    const float* lin_W  = (const float*)d_in[12];
    const float* lin_b  = (const float*)d_in[13];
    float* out = (float*)d_out;

    const int V = in_sizes[3] / 256;     // vocab (32000)
    const size_t nh = (size_t)BB * NNODES * HD;

    char* ws = (char*)d_ws;
    size_t off = 0;
    auto alloc = [&](size_t bytes) -> void* {
        void* p = ws + off;
        off += (bytes + 255) & ~(size_t)255;
        return p;
    };
    ushort_t* hhi  = (ushort_t*)alloc(nh * 2);
    ushort_t* hlo  = (ushort_t*)alloc(nh * 2);
    float*    c    = (float*)   alloc(nh * 4);
    ushort_t* ehi  = (ushort_t*)alloc((size_t)V * 256 * 2);
    ushort_t* elo  = (ushort_t*)alloc((size_t)V * 256 * 2);
    ushort_t* wchi = (ushort_t*)alloc((size_t)LDCOMB * 512 * 2);
    ushort_t* wclo = (ushort_t*)alloc((size_t)LDCOMB * 512 * 2);
    ushort_t* wihi = (ushort_t*)alloc((size_t)IOU3 * 256 * 2);
    ushort_t* wilo = (ushort_t*)alloc((size_t)IOU3 * 256 * 2);
    int*   ids     = (int*)  alloc((size_t)BB * LEAVES * 4);
    float* v       = (float*)alloc((size_t)BB * HD * 4);
    float* scores  = (float*)alloc((size_t)BB * NNODES * 4);
    float* attn    = (float*)alloc((size_t)BB * NNODES * 4);
    float* partial = (float*)alloc((size_t)BB * 8 * HD * 4);

    size_t remain = (ws_size > off) ? (ws_size - off) : 0;
    size_t rows = remain / (LDCOMB * 4);
    int CH = (int)((rows > 16384) ? 16384 : rows);
    CH &= ~127;
    if (CH < 128) CH = 128;
    float* buf = (float*)alloc((size_t)CH * LDCOMB * 4);

    // ---- one-time splits ----
    k_split4<<<(V * 256 / 4 + 255) / 256, 256, 0, stream>>>(emb, ehi, elo, V * 256 / 4);
    k_build_wcat<<<(1280 * 128 + 255) / 256, 256, 0, stream>>>(Uf_W, U_iou, wchi, wclo);
    k_split4<<<(IOU3 * 256 / 4 + 255) / 256, 256, 0, stream>>>(W_iou, wihi, wilo, IOU3 * 256 / 4);
    k_leaf_ids<<<(BB * LEAVES) / 256, 256, 0, stream>>>(wordid, ids);

    // ---- leaves: gather GEMM (K=256, N=768) + apply ----
    {
        int M = BB * LEAVES;
        for (int m0 = 0; m0 < M; m0 += CH) {
            int Mc = M - m0; if (Mc > CH) Mc = CH;
            dim3 g(Mc / BM, IOU3 / BN);
            gemm_mfma<<<g, 512, 0, stream>>>(ehi, elo, ids, 0, 0u, 0, m0, 256,
                                             wihi, wilo, buf, IOU3);
            k_apply_leaf<<<Mc, 256, 0, stream>>>(buf, b_iou, c0, hhi, hlo, c, m0);
        }
    }

    // ---- internal levels, deepest first: fused [Uf;U_iou] GEMM (K=512,N=1280) ----
    for (int L = 8; L >= 0; --L) {
        int npar = 1 << L;
        int ps = (1 << L) - 1;
        int cs = (1 << (L + 1)) - 1;
        int M = BB * npar;
        unsigned sB = NNODES * HD;          // batch stride in h (elements)
        int sP = 2 * HD;                    // parent stride (children contiguous)
        const ushort_t* Abh = hhi + (size_t)cs * HD;
        const ushort_t* Abl = hlo + (size_t)cs * HD;
        for (int m0 = 0; m0 < M; m0 += CH) {
            int Mc = M - m0; if (Mc > CH) Mc = CH;
            dim3 g(Mc / BM, LDCOMB / BN);
            gemm_mfma<<<g, 512, 0, stream>>>(Abh, Abl, (const int*)nullptr, L, sB, sP,
                                             m0, CAT2, wchi, wclo, buf, LDCOMB);
            k_apply_level<<<Mc, 256, 0, stream>>>(buf, b_iou, Uf_b, hhi, hlo, c,
                                                  m0, L, ps, cs);
        }
    }

    // ---- attention + head ----
    k_dec_v<<<BB, HD, 0, stream>>>(hhi, hlo, Wmem, v);
    k_scores<<<dim3(BB, 256), 256, 0, stream>>>(hhi, hlo, v, scores);
    k_softmax<<<BB, 256, 0, stream>>>(scores, attn);
    k_context<<<dim3(BB, 8), HD, 0, stream>>>(hhi, hlo, attn, partial);
    k_final<<<BB, HD, 0, stream>>>(partial, wh_W, wh_b, lin_W, lin_b, out);
}

// Round 7
// 804.521 us; speedup vs baseline: 2.7927x; 2.7927x over previous
//
#include <hip/hip_runtime.h>
#include <math.h>

// Problem constants
#define BB      128
#define NNODES  1023
#define HD      256
#define LEAVES  512
#define IOU3    768     // 3*H
#define CAT2    512     // 2*H
#define LDCOMB  1280    // f(512) + iou(768)

typedef unsigned short ushort_t;
typedef __bf16 bf16x8 __attribute__((ext_vector_type(8)));
typedef float  f32x4  __attribute__((ext_vector_type(4)));

__device__ __forceinline__ float sigf(float x) { return 1.0f / (1.0f + expf(-x)); }

// async global->LDS DMA, 16B per lane, linear dest (base + lane*16)
__device__ __forceinline__ void gload16(const void* g, void* l)
{
    __builtin_amdgcn_global_load_lds(
        (const __attribute__((address_space(1))) unsigned int*)g,
        (__attribute__((address_space(3))) unsigned int*)l, 16, 0, 0);
}

// split fp32 -> bf16 hi + bf16 lo (round-to-nearest-even, bit ops)
__device__ __forceinline__ void split_bf16(float x, ushort_t& h, ushort_t& l)
{
    unsigned u = __float_as_uint(x);
    unsigned r = u + 0x7fff + ((u >> 16) & 1);
    h = (ushort_t)(r >> 16);
    float fh = __uint_as_float((unsigned)h << 16);
    float d = x - fh;
    unsigned u2 = __float_as_uint(d);
    unsigned r2 = u2 + 0x7fff + ((u2 >> 16) & 1);
    l = (ushort_t)(r2 >> 16);
}

__device__ __forceinline__ float rh2(ushort_t h, ushort_t l)
{
    return __uint_as_float((unsigned)h << 16) + __uint_as_float((unsigned)l << 16);
}

// ---------------------------------------------------------------------------
// generic fp32 array -> hi/lo bf16 arrays (4 elements/thread)
// ---------------------------------------------------------------------------
__global__ void k_split4(const float* __restrict__ src, ushort_t* __restrict__ hi,
                         ushort_t* __restrict__ lo, int n4)
{
    int i = blockIdx.x * 256 + threadIdx.x;
    if (i >= n4) return;
    float4 v = ((const float4*)src)[i];
    ushort4 hv, lv;
    split_bf16(v.x, hv.x, lv.x);
    split_bf16(v.y, hv.y, lv.y);
    split_bf16(v.z, hv.z, lv.z);
    split_bf16(v.w, hv.w, lv.w);
    ((ushort4*)hi)[i] = hv;
    ((ushort4*)lo)[i] = lv;
}

// build Wcat = [Uf_W(512 rows) ; U_iou(768 rows)], K=512, as hi/lo bf16
__global__ void k_build_wcat(const float* __restrict__ Uf, const float* __restrict__ Ui,
                             ushort_t* __restrict__ hi, ushort_t* __restrict__ lo)
{
    int i = blockIdx.x * 256 + threadIdx.x;       // over 1280*128 float4s
    if (i >= 1280 * 128) return;
    int row = i >> 7, c4 = i & 127;
    const float* src = (row < 512) ? (Uf + (size_t)row * 512)
                                   : (Ui + (size_t)(row - 512) * 512);
    float4 v = ((const float4*)src)[c4];
    ushort4 hv, lv;
    split_bf16(v.x, hv.x, lv.x);
    split_bf16(v.y, hv.y, lv.y);
    split_bf16(v.z, hv.z, lv.z);
    split_bf16(v.w, hv.w, lv.w);
    ((ushort4*)hi)[i] = hv;
    ((ushort4*)lo)[i] = lv;
}

// ---------------------------------------------------------------------------
// MFMA split-bf16 GEMM:  C[m][n] = sum_k A[m][k]*W[n][k]  (fp32-accurate)
// Block 128x128, BK=32, 256 threads = 4 waves (2m x 2n), wave tile 64x64
// (16 ds_read_b128 -> 48 MFMA per K-step). Staging via global_load_lds DMA
// (no ds_write / no reg round-trip), double-buffered 64KB LDS, ONE barrier
// per K-step (m97 structure). 2 blocks/CU; slab swizzle keeps per-XCD set
// = ~7 A panels + full B < 4MB L2 (rounds 3/6 lesson: gy must stay 10,
// per-XCD A set small).
// Swizzle discipline (rule #21): DMA dest linear, global SOURCE pre-permuted
// (slot' = slot ^ ((row>>1)&3)), ds_read applies same involution.
// ---------------------------------------------------------------------------
#define BM 128
#define BN 128
#define BK 32

__global__ __launch_bounds__(256, 2)
void gemm_mfma(const ushort_t* __restrict__ Ahi, const ushort_t* __restrict__ Alo,
               const int* __restrict__ ids,
               int lognpar, unsigned sB, int sP, int m0, int K,
               const ushort_t* __restrict__ Bhi, const ushort_t* __restrict__ Blo,
               float* __restrict__ C, int ldc)
{
    __shared__ __align__(16) char lds[65536];
    const int tid = threadIdx.x;

    // slab-ordered, XCD-preserving block swizzle
    int bx = blockIdx.x, by = blockIdx.y;
    {
        const int gx = gridDim.x, gy = gridDim.y;
        if ((gx & 7) == 0) {
            int f = by * gx + bx;        // HW dispatch order (x fastest)
            int span = gy << 3;          // 8 * gy blocks per slab
            int s = f / span;
            int wv = f - s * span;
            bx = (s << 3) + (wv & 7);    // bx % 8 == f % 8 -> same XCD
            by = wv >> 3;
        }
    }

    const int w = tid >> 6, lane = tid & 63;

    // ---- DMA staging setup: wave w stages rows [w*32, w*32+32) of A and B.
    // instr pair p in {0,1}: rows w*32+p*16+(lane>>2), slot = lane&3,
    // source slot' = slot ^ ((row>>1)&3)  (inverse-swizzled source).
    unsigned aofs[2], bofs[2];
    int dofs[2];                                   // uniform LDS instr offsets
#pragma unroll
    for (int p = 0; p < 2; ++p) {
        int row = w * 32 + p * 16 + (lane >> 2);
        int slotp = (lane & 3) ^ ((row >> 1) & 3);
        int mg = m0 + bx * BM + row;
        unsigned ab;
        if (ids) {
            ab = (unsigned)ids[mg] * (unsigned)K;
        } else {
            int b = mg >> lognpar;
            int q = mg & ((1 << lognpar) - 1);
            ab = (unsigned)b * sB + (unsigned)q * (unsigned)sP;
        }
        aofs[p] = ab + slotp * 8;
        bofs[p] = (unsigned)(by * BN + row) * (unsigned)K + slotp * 8;
        dofs[p] = w * 2048 + p * 1024;             // (w*32+p*16) rows * 64B
    }

    auto STAGE = [&](int k0, char* buf) {
#pragma unroll
        for (int p = 0; p < 2; ++p) {
            gload16(Ahi + aofs[p] + k0, buf +     0 + dofs[p]);
            gload16(Alo + aofs[p] + k0, buf +  8192 + dofs[p]);
            gload16(Bhi + bofs[p] + k0, buf + 16384 + dofs[p]);
            gload16(Blo + bofs[p] + k0, buf + 24576 + dofs[p]);
        }
    };

    // fragment read addresses: 4 waves as 2(m) x 2(n); wave tile 64x64
    const int wm = w >> 1, wn = w & 1;
    const int rA0 = wm * 64 + (lane & 15);
    const int rB0 = wn * 64 + (lane & 15);
    const int ko = lane >> 4;
    const int rdA = rA0 * 64 + ((ko ^ ((rA0 >> 1) & 3)) << 4);
    const int rdB = rB0 * 64 + ((ko ^ ((rB0 >> 1) & 3)) << 4);

    f32x4 acc[4][4];
#pragma unroll
    for (int mi = 0; mi < 4; ++mi)
#pragma unroll
        for (int ni = 0; ni < 4; ++ni) acc[mi][ni] = (f32x4){0.f, 0.f, 0.f, 0.f};

    const int nt = K / BK;
    STAGE(0, lds);
    __syncthreads();                               // vmcnt(0) drain + barrier
    int cur = 0;
    for (int t = 0; t < nt; ++t) {
        if (t + 1 < nt) STAGE((t + 1) * BK, lds + (cur ^ 1) * 32768);
        char* base = lds + cur * 32768;
        bf16x8 ah[4], al[4], bh[4], bl[4];
#pragma unroll
        for (int f = 0; f < 4; ++f) {
            ah[f] = *(const bf16x8*)(base +         rdA + f * 1024);
            al[f] = *(const bf16x8*)(base +  8192 + rdA + f * 1024);
            bh[f] = *(const bf16x8*)(base + 16384 + rdB + f * 1024);
            bl[f] = *(const bf16x8*)(base + 24576 + rdB + f * 1024);
        }
        __builtin_amdgcn_s_setprio(1);
#pragma unroll
        for (int mi = 0; mi < 4; ++mi)
#pragma unroll
            for (int ni = 0; ni < 4; ++ni) {
                acc[mi][ni] = __builtin_amdgcn_mfma_f32_16x16x32_bf16(ah[mi], bh[ni], acc[mi][ni], 0, 0, 0);
                acc[mi][ni] = __builtin_amdgcn_mfma_f32_16x16x32_bf16(ah[mi], bl[ni], acc[mi][ni], 0, 0, 0);
                acc[mi][ni] = __builtin_amdgcn_mfma_f32_16x16x32_bf16(al[mi], bh[ni], acc[mi][ni], 0, 0, 0);
            }
        __builtin_amdgcn_s_setprio(0);
        __syncthreads();       // drains vmcnt (t+1 DMA done, issued ~MFMA ago)
        cur ^= 1;              // + all reads of cur complete
    }

    // ---- epilogue: per-wave repack through LDS -> 256B-contiguous stores ----
    // wave w uses lds[w*4352 .. +4352): 16 rows x 272B (64 floats + 4 pad)
    {
        char* patch = lds + w * 4352;
        const int cl = lane & 15, rg = lane >> 4;
        const int gcol0 = by * BN + wn * 64;
#pragma unroll
        for (int mi = 0; mi < 4; ++mi) {
#pragma unroll
            for (int ni = 0; ni < 4; ++ni)
#pragma unroll
                for (int r = 0; r < 4; ++r)
                    *(float*)(patch + (rg * 4 + r) * 272 + (ni * 16 + cl) * 4) = acc[mi][ni][r];
            int grow0 = bx * BM + wm * 64 + mi * 16;
#pragma unroll
            for (int it = 0; it < 4; ++it) {
                int lr = it * 4 + rg;
                f32x4 vv = *(const f32x4*)(patch + lr * 272 + cl * 16);
                *(f32x4*)(C + (size_t)(grow0 + lr) * ldc + gcol0 + cl * 4) = vv;
            }
        }
    }
}

// ---------------------------------------------------------------------------
// leaf id gather
// ---------------------------------------------------------------------------
__global__ void k_leaf_ids(const int* __restrict__ wordid, int* __restrict__ ids)
{
    int idx = blockIdx.x * 256 + threadIdx.x;   // 65536 total
    int b = idx >> 9, leaf = idx & 511;
    ids[idx] = wordid[b * NNODES + 511 + leaf];
}

// ---------------------------------------------------------------------------
// leaf apply: buf[m][768] (iou) -> h(hi/lo), c at node 511+leaf
// ---------------------------------------------------------------------------
__global__ void k_apply_leaf(const float* __restrict__ buf, const float* __restrict__ b_iou,
                             const float* __restrict__ c0,
                             ushort_t* __restrict__ hhi, ushort_t* __restrict__ hlo,
                             float* __restrict__ c, int m0)
{
    int idx = blockIdx.x * 256 + threadIdx.x;
    int m_l = idx >> 8, hh = idx & 255;
    int mg = m0 + m_l;
    int b = mg >> 9, leaf = mg & 511;
    int node = 511 + leaf;
    const float* br = buf + (size_t)m_l * IOU3;
    float iv = br[hh]        + b_iou[hh];
    float ov = br[256 + hh]  + b_iou[256 + hh];
    float uv = br[512 + hh]  + b_iou[512 + hh];
    size_t nb = ((size_t)b * NNODES + node) * HD + hh;
    float cn = sigf(iv) * tanhf(uv) + c0[nb];
    float hn = sigf(ov) * tanhf(cn);
    c[nb] = cn;
    split_bf16(hn, hhi[nb], hlo[nb]);
}

// ---------------------------------------------------------------------------
// level apply: buf[m][1280] = [f_l | f_r | i | o | u]
// ---------------------------------------------------------------------------
__global__ void k_apply_level(const float* __restrict__ buf, const float* __restrict__ b_iou,
                              const float* __restrict__ Uf_b,
                              ushort_t* __restrict__ hhi, ushort_t* __restrict__ hlo,
                              float* __restrict__ c,
                              int m0, int lognpar, int ps, int cs)
{
    int idx = blockIdx.x * 256 + threadIdx.x;
    int m_l = idx >> 8, hh = idx & 255;
    int mg = m0 + m_l;
    int b = mg >> lognpar;
    int p = mg & ((1 << lognpar) - 1);
    const float* br = buf + (size_t)m_l * LDCOMB;
    float fl = sigf(br[hh]        + Uf_b[hh]);
    float fr = sigf(br[256 + hh]  + Uf_b[256 + hh]);
    size_t cb = ((size_t)b * NNODES + cs + 2 * p) * HD + hh;
    float csum = fl * c[cb] + fr * c[cb + HD];
    float iv = br[512 + hh]  + b_iou[hh];
    float ov = br[768 + hh]  + b_iou[256 + hh];
    float uv = br[1024 + hh] + b_iou[512 + hh];
    float cn = sigf(iv) * tanhf(uv) + csum;
    float hn = sigf(ov) * tanhf(cn);
    size_t pb = ((size_t)b * NNODES + ps + p) * HD + hh;
    c[pb] = cn;
    split_bf16(hn, hhi[pb], hlo[pb]);
}

// ---------------------------------------------------------------------------
// v[b][k] = sum_g h[b][0][g] * Wmem[g][k]
// ---------------------------------------------------------------------------
__global__ void k_dec_v(const ushort_t* __restrict__ hhi, const ushort_t* __restrict__ hlo,
                        const float* __restrict__ Wmem, float* __restrict__ v)
{
    int b = blockIdx.x, k = threadIdx.x;
    __shared__ float dec[HD];
    size_t base = (size_t)b * NNODES * HD;
    dec[k] = rh2(hhi[base + k], hlo[base + k]);
    __syncthreads();
    float s = 0.f;
    for (int g = 0; g < HD; ++g) s = fmaf(dec[g], Wmem[g * HD + k], s);
    v[b * HD + k] = s;
}

// ---------------------------------------------------------------------------
// scores[b][n] = v_b . h[b][n]
// ---------------------------------------------------------------------------
__global__ void k_scores(const ushort_t* __restrict__ hhi, const ushort_t* __restrict__ hlo,
                         const float* __restrict__ v, float* __restrict__ scores)
{
    int b = blockIdx.x;
    int w = threadIdx.x >> 6, lane = threadIdx.x & 63;
    int n = blockIdx.y * 4 + w;
    if (n >= NNODES) return;
    size_t hb = ((size_t)b * NNODES + n) * HD;
    ushort4 ph = *(const ushort4*)(hhi + hb + lane * 4);
    ushort4 pl = *(const ushort4*)(hlo + hb + lane * 4);
    float4 vv = *(const float4*)(v + b * HD + lane * 4);
    float s = rh2(ph.x, pl.x) * vv.x + rh2(ph.y, pl.y) * vv.y +
              rh2(ph.z, pl.z) * vv.z + rh2(ph.w, pl.w) * vv.w;
#pragma unroll
    for (int o = 32; o; o >>= 1) s += __shfl_down(s, o);
    if (lane == 0) scores[(size_t)b * NNODES + n] = s;
}

// ---------------------------------------------------------------------------
// softmax over n (1023) per batch row
// ---------------------------------------------------------------------------
__global__ void k_softmax(const float* __restrict__ scores, float* __restrict__ attn)
{
    int b = blockIdx.x, t = threadIdx.x;
    __shared__ float red[4];
    float sv[4];
    float m = -INFINITY;
#pragma unroll
    for (int i = 0; i < 4; ++i) {
        int n = t + 256 * i;
        sv[i] = (n < NNODES) ? scores[(size_t)b * NNODES + n] : -INFINITY;
        m = fmaxf(m, sv[i]);
    }
#pragma unroll
    for (int o = 32; o; o >>= 1) m = fmaxf(m, __shfl_xor(m, o));
    int w = t >> 6, lane = t & 63;
    if (lane == 0) red[w] = m;
    __syncthreads();
    m = fmaxf(fmaxf(red[0], red[1]), fmaxf(red[2], red[3]));
    float s = 0.f;
#pragma unroll
    for (int i = 0; i < 4; ++i) {
        int n = t + 256 * i;
        sv[i] = (n < NNODES) ? expf(sv[i] - m) : 0.f;
        s += sv[i];
    }
#pragma unroll
    for (int o = 32; o; o >>= 1) s += __shfl_xor(s, o);
    __syncthreads();
    if (lane == 0) red[w] = s;
    __syncthreads();
    s = red[0] + red[1] + red[2] + red[3];
    float inv = 1.0f / s;
#pragma unroll
    for (int i = 0; i < 4; ++i) {
        int n = t + 256 * i;
        if (n < NNODES) attn[(size_t)b * NNODES + n] = sv[i] * inv;
    }
}

// ---------------------------------------------------------------------------
// context partials
// ---------------------------------------------------------------------------
__global__ void k_context(const ushort_t* __restrict__ hhi, const ushort_t* __restrict__ hlo,
                          const float* __restrict__ attn, float* __restrict__ partial)
{
    int b = blockIdx.x, ch = blockIdx.y, k = threadIdx.x;
    int n0 = ch * 128;
    int n1 = n0 + 128; if (n1 > NNODES) n1 = NNODES;
    float s = 0.f;
    for (int n = n0; n < n1; ++n) {
        size_t i = ((size_t)b * NNODES + n) * HD + k;
        s = fmaf(attn[(size_t)b * NNODES + n], rh2(hhi[i], hlo[i]), s);
    }
    partial[((size_t)b * 8 + ch) * HD + k] = s;
}

// ---------------------------------------------------------------------------
// final head
// ---------------------------------------------------------------------------
__global__ void k_final(const float* __restrict__ partial,
                        const float* __restrict__ wh_W, const float* __restrict__ wh_b,
                        const float* __restrict__ lin_W, const float* __restrict__ lin_b,
                        float* __restrict__ out)
{
    int b = blockIdx.x, j = threadIdx.x;
    __shared__ float ctx[HD];
    __shared__ float hid[HD];
    float s = 0.f;
#pragma unroll
    for (int ch = 0; ch < 8; ++ch) s += partial[((size_t)b * 8 + ch) * HD + j];
    ctx[j] = s;
    __syncthreads();
    float a = wh_b[j];
    for (int k = 0; k < HD; ++k) a = fmaf(ctx[k], wh_W[j * HD + k], a);
    hid[j] = fmaxf(a, 0.f);
    __syncthreads();
    if (j < 10) {
        float o = lin_b[j];
        for (int k = 0; k < HD; ++k) o = fmaf(hid[k], lin_W[j * HD + k], o);
        out[b * 10 + j] = o;
    }
}

// ---------------------------------------------------------------------------
extern "C" void kernel_launch(void* const* d_in, const int* in_sizes, int n_in,
                              void* d_out, int out_size, void* d_ws, size_t ws_size,
                              hipStream_t stream)
{
    const int*   wordid = (const int*)d_in[0];
    const float* c0     = (const float*)d_in[2];
    const float* emb    = (const float*)d_in[3];
    const float* W_iou  = (const float*)d_in[4];
    const float* U_iou  = (const float*)d_in[5];
    const float* b_iou  = (const float*)d_in[6];
    const float* Uf_W   = (const float*)d_in[7];
    const float* Uf_b   = (const float*)d_in[8];
    const float* Wmem   = (const float*)d_in[9];
    const float* wh_W   = (const float*)d_in[10];
    const float* wh_b   = (const float*)d_in[11];
    const float* lin_W  = (const float*)d_in[12];
    const float* lin_b  = (const float*)d_in[13];
    float* out = (float*)d_out;

    const int V = in_sizes[3] / 256;     // vocab (32000)
    const size_t nh = (size_t)BB * NNODES * HD;

    char* ws = (char*)d_ws;
    size_t off = 0;
    auto alloc = [&](size_t bytes) -> void* {
        void* p = ws + off;
        off += (bytes + 255) & ~(size_t)255;
        return p;
    };
    ushort_t* hhi  = (ushort_t*)alloc(nh * 2);
    ushort_t* hlo  = (ushort_t*)alloc(nh * 2);
    float*    c    = (float*)   alloc(nh * 4);
    ushort_t* ehi  = (ushort_t*)alloc((size_t)V * 256 * 2);
    ushort_t* elo  = (ushort_t*)alloc((size_t)V * 256 * 2);
    ushort_t* wchi = (ushort_t*)alloc((size_t)LDCOMB * 512 * 2);
    ushort_t* wclo = (ushort_t*)alloc((size_t)LDCOMB * 512 * 2);
    ushort_t* wihi = (ushort_t*)alloc((size_t)IOU3 * 256 * 2);
    ushort_t* wilo = (ushort_t*)alloc((size_t)IOU3 * 256 * 2);
    int*   ids     = (int*)  alloc((size_t)BB * LEAVES * 4);
    float* v       = (float*)alloc((size_t)BB * HD * 4);
    float* scores  = (float*)alloc((size_t)BB * NNODES * 4);
    float* attn    = (float*)alloc((size_t)BB * NNODES * 4);
    float* partial = (float*)alloc((size_t)BB * 8 * HD * 4);

    size_t remain = (ws_size > off) ? (ws_size - off) : 0;
    size_t rows = remain / (LDCOMB * 4);
    int CH = (int)((rows > 16384) ? 16384 : rows);
    CH &= ~127;
    if (CH < 128) CH = 128;
    float* buf = (float*)alloc((size_t)CH * LDCOMB * 4);

    // ---- one-time splits ----
    k_split4<<<(V * 256 / 4 + 255) / 256, 256, 0, stream>>>(emb, ehi, elo, V * 256 / 4);
    k_build_wcat<<<(1280 * 128 + 255) / 256, 256, 0, stream>>>(Uf_W, U_iou, wchi, wclo);
    k_split4<<<(IOU3 * 256 / 4 + 255) / 256, 256, 0, stream>>>(W_iou, wihi, wilo, IOU3 * 256 / 4);
    k_leaf_ids<<<(BB * LEAVES) / 256, 256, 0, stream>>>(wordid, ids);

    // ---- leaves: gather GEMM (K=256, N=768) + apply ----
    {
        int M = BB * LEAVES;
        for (int m0 = 0; m0 < M; m0 += CH) {
            int Mc = M - m0; if (Mc > CH) Mc = CH;
            dim3 g(Mc / BM, IOU3 / BN);
            gemm_mfma<<<g, 256, 0, stream>>>(ehi, elo, ids, 0, 0u, 0, m0, 256,
                                             wihi, wilo, buf, IOU3);
            k_apply_leaf<<<Mc, 256, 0, stream>>>(buf, b_iou, c0, hhi, hlo, c, m0);
        }
    }

    // ---- internal levels, deepest first: fused [Uf;U_iou] GEMM (K=512,N=1280) ----
    for (int L = 8; L >= 0; --L) {
        int npar = 1 << L;
        int ps = (1 << L) - 1;
        int cs = (1 << (L + 1)) - 1;
        int M = BB * npar;
        unsigned sB = NNODES * HD;          // batch stride in h (elements)
        int sP = 2 * HD;                    // parent stride (children contiguous)
        const ushort_t* Abh = hhi + (size_t)cs * HD;
        const ushort_t* Abl = hlo + (size_t)cs * HD;
        for (int m0 = 0; m0 < M; m0 += CH) {
            int Mc = M - m0; if (Mc > CH) Mc = CH;
            dim3 g(Mc / BM, LDCOMB / BN);
            gemm_mfma<<<g, 256, 0, stream>>>(Abh, Abl, (const int*)nullptr, L, sB, sP,
                                             m0, CAT2, wchi, wclo, buf, LDCOMB);
            k_apply_level<<<Mc, 256, 0, stream>>>(buf, b_iou, Uf_b, hhi, hlo, c,
                                                  m0, L, ps, cs);
        }
    }

    // ---- attention + head ----
    k_dec_v<<<BB, HD, 0, stream>>>(hhi, hlo, Wmem, v);
    k_scores<<<dim3(BB, 256), 256, 0, stream>>>(hhi, hlo, v, scores);
    k_softmax<<<BB, 256, 0, stream>>>(scores, attn);
    k_context<<<dim3(BB, 8), HD, 0, stream>>>(hhi, hlo, attn, partial);
    k_final<<<BB, HD, 0, stream>>>(partial, wh_W, wh_b, lin_W, lin_b, out);
}

// Round 8
// 777.356 us; speedup vs baseline: 2.8903x; 1.0349x over previous
//
#include <hip/hip_runtime.h>
#include <math.h>

// Problem constants
#define BB      128
#define NNODES  1023
#define HD      256
#define LEAVES  512
#define IOU3    768     // 3*H
#define CAT2    512     // 2*H
#define LDCOMB  1280    // f(512) + iou(768)

typedef unsigned short ushort_t;
typedef __bf16 bf16x8 __attribute__((ext_vector_type(8)));
typedef float  f32x4  __attribute__((ext_vector_type(4)));

__device__ __forceinline__ float sigf(float x) { return 1.0f / (1.0f + expf(-x)); }

// async global->LDS DMA, 16B per lane, linear dest (base + lane*16)
__device__ __forceinline__ void gload16(const void* g, void* l)
{
    __builtin_amdgcn_global_load_lds(
        (const __attribute__((address_space(1))) unsigned int*)g,
        (__attribute__((address_space(3))) unsigned int*)l, 16, 0, 0);
}

// split fp32 -> bf16 hi + bf16 lo (round-to-nearest-even, bit ops)
__device__ __forceinline__ void split_bf16(float x, ushort_t& h, ushort_t& l)
{
    unsigned u = __float_as_uint(x);
    unsigned r = u + 0x7fff + ((u >> 16) & 1);
    h = (ushort_t)(r >> 16);
    float fh = __uint_as_float((unsigned)h << 16);
    float d = x - fh;
    unsigned u2 = __float_as_uint(d);
    unsigned r2 = u2 + 0x7fff + ((u2 >> 16) & 1);
    l = (ushort_t)(r2 >> 16);
}

__device__ __forceinline__ float rh2(ushort_t h, ushort_t l)
{
    return __uint_as_float((unsigned)h << 16) + __uint_as_float((unsigned)l << 16);
}

// ---------------------------------------------------------------------------
// generic fp32 array -> hi/lo bf16 arrays (4 elements/thread)
// ---------------------------------------------------------------------------
__global__ void k_split4(const float* __restrict__ src, ushort_t* __restrict__ hi,
                         ushort_t* __restrict__ lo, int n4)
{
    int i = blockIdx.x * 256 + threadIdx.x;
    if (i >= n4) return;
    float4 v = ((const float4*)src)[i];
    ushort4 hv, lv;
    split_bf16(v.x, hv.x, lv.x);
    split_bf16(v.y, hv.y, lv.y);
    split_bf16(v.z, hv.z, lv.z);
    split_bf16(v.w, hv.w, lv.w);
    ((ushort4*)hi)[i] = hv;
    ((ushort4*)lo)[i] = lv;
}

// build Wcat = [Uf_W(512 rows) ; U_iou(768 rows)], K=512, as hi/lo bf16
__global__ void k_build_wcat(const float* __restrict__ Uf, const float* __restrict__ Ui,
                             ushort_t* __restrict__ hi, ushort_t* __restrict__ lo)
{
    int i = blockIdx.x * 256 + threadIdx.x;       // over 1280*128 float4s
    if (i >= 1280 * 128) return;
    int row = i >> 7, c4 = i & 127;
    const float* src = (row < 512) ? (Uf + (size_t)row * 512)
                                   : (Ui + (size_t)(row - 512) * 512);
    float4 v = ((const float4*)src)[c4];
    ushort4 hv, lv;
    split_bf16(v.x, hv.x, lv.x);
    split_bf16(v.y, hv.y, lv.y);
    split_bf16(v.z, hv.z, lv.z);
    split_bf16(v.w, hv.w, lv.w);
    ((ushort4*)hi)[i] = hv;
    ((ushort4*)lo)[i] = lv;
}

// ---------------------------------------------------------------------------
// MFMA split-bf16 GEMM:  C[m][n] = sum_k A[m][k]*W[n][k]  (fp32-accurate)
// Block 128x128, BK=32, 256 threads = 4 waves (2m x 2n), wave tile 64x64.
// global_load_lds DMA staging, double-buffered 64KB LDS.
// T4 counted-vmcnt pipeline: per K-step
//   STAGE(t+1 -> buf^1); vmcnt(8) [stage-t landed]; s_barrier;
//   ds_read buf + MFMA; s_barrier [reads done before overwrite].
// Next-tile DMA stays in flight across both barriers (never drain to 0
// except last iter). 2 blocks/CU; slab swizzle keeps per-XCD set < 4MB L2
// (rounds 3/6 lesson: per-XCD A-panel set must stay small, gy=10).
// Swizzle discipline (rule #21): DMA dest linear, global SOURCE pre-permuted
// (slot' = slot ^ ((row>>1)&3)), ds_read applies same involution.
// ---------------------------------------------------------------------------
#define BM 128
#define BN 128
#define BK 32

__global__ __launch_bounds__(256, 2)
void gemm_mfma(const ushort_t* __restrict__ Ahi, const ushort_t* __restrict__ Alo,
               const int* __restrict__ ids,
               int lognpar, unsigned sB, int sP, int m0, int K,
               const ushort_t* __restrict__ Bhi, const ushort_t* __restrict__ Blo,
               float* __restrict__ C, int ldc)
{
    __shared__ __align__(16) char lds[65536];
    const int tid = threadIdx.x;

    // slab-ordered, XCD-preserving block swizzle
    int bx = blockIdx.x, by = blockIdx.y;
    {
        const int gx = gridDim.x, gy = gridDim.y;
        if ((gx & 7) == 0) {
            int f = by * gx + bx;        // HW dispatch order (x fastest)
            int span = gy << 3;          // 8 * gy blocks per slab
            int s = f / span;
            int wv = f - s * span;
            bx = (s << 3) + (wv & 7);    // bx % 8 == f % 8 -> same XCD
            by = wv >> 3;
        }
    }

    const int w = tid >> 6, lane = tid & 63;

    // ---- DMA staging setup: wave w stages rows [w*32, w*32+32) of A and B.
    unsigned aofs[2], bofs[2];
    int dofs[2];                                   // uniform LDS instr offsets
#pragma unroll
    for (int p = 0; p < 2; ++p) {
        int row = w * 32 + p * 16 + (lane >> 2);
        int slotp = (lane & 3) ^ ((row >> 1) & 3);
        int mg = m0 + bx * BM + row;
        unsigned ab;
        if (ids) {
            ab = (unsigned)ids[mg] * (unsigned)K;
        } else {
            int b = mg >> lognpar;
            int q = mg & ((1 << lognpar) - 1);
            ab = (unsigned)b * sB + (unsigned)q * (unsigned)sP;
        }
        aofs[p] = ab + slotp * 8;
        bofs[p] = (unsigned)(by * BN + row) * (unsigned)K + slotp * 8;
        dofs[p] = w * 2048 + p * 1024;             // (w*32+p*16) rows * 64B
    }

    auto STAGE = [&](int k0, char* buf) {
#pragma unroll
        for (int p = 0; p < 2; ++p) {
            gload16(Ahi + aofs[p] + k0, buf +     0 + dofs[p]);
            gload16(Alo + aofs[p] + k0, buf +  8192 + dofs[p]);
            gload16(Bhi + bofs[p] + k0, buf + 16384 + dofs[p]);
            gload16(Blo + bofs[p] + k0, buf + 24576 + dofs[p]);
        }
    };

    // fragment read addresses: 4 waves as 2(m) x 2(n); wave tile 64x64
    const int wm = w >> 1, wn = w & 1;
    const int rA0 = wm * 64 + (lane & 15);
    const int rB0 = wn * 64 + (lane & 15);
    const int ko = lane >> 4;
    const int rdA = rA0 * 64 + ((ko ^ ((rA0 >> 1) & 3)) << 4);
    const int rdB = rB0 * 64 + ((ko ^ ((rB0 >> 1) & 3)) << 4);

    f32x4 acc[4][4];
#pragma unroll
    for (int mi = 0; mi < 4; ++mi)
#pragma unroll
        for (int ni = 0; ni < 4; ++ni) acc[mi][ni] = (f32x4){0.f, 0.f, 0.f, 0.f};

    const int nt = K / BK;
    STAGE(0, lds);
    int cur = 0;
    for (int t = 0; t < nt; ++t) {
        if (t + 1 < nt) {
            STAGE((t + 1) * BK, lds + (cur ^ 1) * 32768);
            asm volatile("s_waitcnt vmcnt(8)" ::: "memory");   // stage-t landed
        } else {
            asm volatile("s_waitcnt vmcnt(0)" ::: "memory");   // final drain
        }
        __builtin_amdgcn_s_barrier();          // all waves: buf[cur] ready
        __builtin_amdgcn_sched_barrier(0);
        char* base = lds + cur * 32768;
        bf16x8 ah[4], al[4], bh[4], bl[4];
#pragma unroll
        for (int f = 0; f < 4; ++f) {
            ah[f] = *(const bf16x8*)(base +         rdA + f * 1024);
            al[f] = *(const bf16x8*)(base +  8192 + rdA + f * 1024);
            bh[f] = *(const bf16x8*)(base + 16384 + rdB + f * 1024);
            bl[f] = *(const bf16x8*)(base + 24576 + rdB + f * 1024);
        }
        __builtin_amdgcn_s_setprio(1);
#pragma unroll
        for (int mi = 0; mi < 4; ++mi)
#pragma unroll
            for (int ni = 0; ni < 4; ++ni) {
                acc[mi][ni] = __builtin_amdgcn_mfma_f32_16x16x32_bf16(ah[mi], bh[ni], acc[mi][ni], 0, 0, 0);
                acc[mi][ni] = __builtin_amdgcn_mfma_f32_16x16x32_bf16(ah[mi], bl[ni], acc[mi][ni], 0, 0, 0);
                acc[mi][ni] = __builtin_amdgcn_mfma_f32_16x16x32_bf16(al[mi], bh[ni], acc[mi][ni], 0, 0, 0);
            }
        __builtin_amdgcn_s_setprio(0);
        __builtin_amdgcn_s_barrier();          // reads of buf[cur] done
        cur ^= 1;
    }

    // ---- epilogue: per-wave repack through LDS -> 256B-contiguous stores ----
    // (safe: last iter drained vmcnt(0) + barrier)
    {
        char* patch = lds + w * 4352;
        const int cl = lane & 15, rg = lane >> 4;
        const int gcol0 = by * BN + wn * 64;
#pragma unroll
        for (int mi = 0; mi < 4; ++mi) {
#pragma unroll
            for (int ni = 0; ni < 4; ++ni)
#pragma unroll
                for (int r = 0; r < 4; ++r)
                    *(float*)(patch + (rg * 4 + r) * 272 + (ni * 16 + cl) * 4) = acc[mi][ni][r];
            int grow0 = bx * BM + wm * 64 + mi * 16;
#pragma unroll
            for (int it = 0; it < 4; ++it) {
                int lr = it * 4 + rg;
                f32x4 vv = *(const f32x4*)(patch + lr * 272 + cl * 16);
                *(f32x4*)(C + (size_t)(grow0 + lr) * ldc + gcol0 + cl * 4) = vv;
            }
        }
    }
}

// ---------------------------------------------------------------------------
// leaf id gather
// ---------------------------------------------------------------------------
__global__ void k_leaf_ids(const int* __restrict__ wordid, int* __restrict__ ids)
{
    int idx = blockIdx.x * 256 + threadIdx.x;   // 65536 total
    int b = idx >> 9, leaf = idx & 511;
    ids[idx] = wordid[b * NNODES + 511 + leaf];
}

// ---------------------------------------------------------------------------
// leaf apply: buf[m][768] (iou) -> h(hi/lo), c at node 511+leaf
// ---------------------------------------------------------------------------
__global__ void k_apply_leaf(const float* __restrict__ buf, const float* __restrict__ b_iou,
                             const float* __restrict__ c0,
                             ushort_t* __restrict__ hhi, ushort_t* __restrict__ hlo,
                             float* __restrict__ c, int m0)
{
    int idx = blockIdx.x * 256 + threadIdx.x;
    int m_l = idx >> 8, hh = idx & 255;
    int mg = m0 + m_l;
    int b = mg >> 9, leaf = mg & 511;
    int node = 511 + leaf;
    const float* br = buf + (size_t)m_l * IOU3;
    float iv = br[hh]        + b_iou[hh];
    float ov = br[256 + hh]  + b_iou[256 + hh];
    float uv = br[512 + hh]  + b_iou[512 + hh];
    size_t nb = ((size_t)b * NNODES + node) * HD + hh;
    float cn = sigf(iv) * tanhf(uv) + c0[nb];
    float hn = sigf(ov) * tanhf(cn);
    c[nb] = cn;
    split_bf16(hn, hhi[nb], hlo[nb]);
}

// ---------------------------------------------------------------------------
// level apply: buf[m][1280] = [f_l | f_r | i | o | u]
// ---------------------------------------------------------------------------
__global__ void k_apply_level(const float* __restrict__ buf, const float* __restrict__ b_iou,
                              const float* __restrict__ Uf_b,
                              ushort_t* __restrict__ hhi, ushort_t* __restrict__ hlo,
                              float* __restrict__ c,
                              int m0, int lognpar, int ps, int cs)
{
    int idx = blockIdx.x * 256 + threadIdx.x;
    int m_l = idx >> 8, hh = idx & 255;
    int mg = m0 + m_l;
    int b = mg >> lognpar;
    int p = mg & ((1 << lognpar) - 1);
    const float* br = buf + (size_t)m_l * LDCOMB;
    float fl = sigf(br[hh]        + Uf_b[hh]);
    float fr = sigf(br[256 + hh]  + Uf_b[256 + hh]);
    size_t cb = ((size_t)b * NNODES + cs + 2 * p) * HD + hh;
    float csum = fl * c[cb] + fr * c[cb + HD];
    float iv = br[512 + hh]  + b_iou[hh];
    float ov = br[768 + hh]  + b_iou[256 + hh];
    float uv = br[1024 + hh] + b_iou[512 + hh];
    float cn = sigf(iv) * tanhf(uv) + csum;
    float hn = sigf(ov) * tanhf(cn);
    size_t pb = ((size_t)b * NNODES + ps + p) * HD + hh;
    c[pb] = cn;
    split_bf16(hn, hhi[pb], hlo[pb]);
}

// ---------------------------------------------------------------------------
// v[b][k] = sum_g h[b][0][g] * Wmem[g][k]
// ---------------------------------------------------------------------------
__global__ void k_dec_v(const ushort_t* __restrict__ hhi, const ushort_t* __restrict__ hlo,
                        const float* __restrict__ Wmem, float* __restrict__ v)
{
    int b = blockIdx.x, k = threadIdx.x;
    __shared__ float dec[HD];
    size_t base = (size_t)b * NNODES * HD;
    dec[k] = rh2(hhi[base + k], hlo[base + k]);
    __syncthreads();
    float s = 0.f;
    for (int g = 0; g < HD; ++g) s = fmaf(dec[g], Wmem[g * HD + k], s);
    v[b * HD + k] = s;
}

// ---------------------------------------------------------------------------
// scores[b][n] = v_b . h[b][n]
// ---------------------------------------------------------------------------
__global__ void k_scores(const ushort_t* __restrict__ hhi, const ushort_t* __restrict__ hlo,
                         const float* __restrict__ v, float* __restrict__ scores)
{
    int b = blockIdx.x;
    int w = threadIdx.x >> 6, lane = threadIdx.x & 63;
    int n = blockIdx.y * 4 + w;
    if (n >= NNODES) return;
    size_t hb = ((size_t)b * NNODES + n) * HD;
    ushort4 ph = *(const ushort4*)(hhi + hb + lane * 4);
    ushort4 pl = *(const ushort4*)(hlo + hb + lane * 4);
    float4 vv = *(const float4*)(v + b * HD + lane * 4);
    float s = rh2(ph.x, pl.x) * vv.x + rh2(ph.y, pl.y) * vv.y +
              rh2(ph.z, pl.z) * vv.z + rh2(ph.w, pl.w) * vv.w;
#pragma unroll
    for (int o = 32; o; o >>= 1) s += __shfl_down(s, o);
    if (lane == 0) scores[(size_t)b * NNODES + n] = s;
}

// ---------------------------------------------------------------------------
// softmax over n (1023) per batch row
// ---------------------------------------------------------------------------
__global__ void k_softmax(const float* __restrict__ scores, float* __restrict__ attn)
{
    int b = blockIdx.x, t = threadIdx.x;
    __shared__ float red[4];
    float sv[4];
    float m = -INFINITY;
#pragma unroll
    for (int i = 0; i < 4; ++i) {
        int n = t + 256 * i;
        sv[i] = (n < NNODES) ? scores[(size_t)b * NNODES + n] : -INFINITY;
        m = fmaxf(m, sv[i]);
    }
#pragma unroll
    for (int o = 32; o; o >>= 1) m = fmaxf(m, __shfl_xor(m, o));
    int w = t >> 6, lane = t & 63;
    if (lane == 0) red[w] = m;
    __syncthreads();
    m = fmaxf(fmaxf(red[0], red[1]), fmaxf(red[2], red[3]));
    float s = 0.f;
#pragma unroll
    for (int i = 0; i < 4; ++i) {
        int n = t + 256 * i;
        sv[i] = (n < NNODES) ? expf(sv[i] - m) : 0.f;
        s += sv[i];
    }
#pragma unroll
    for (int o = 32; o; o >>= 1) s += __shfl_xor(s, o);
    __syncthreads();
    if (lane == 0) red[w] = s;
    __syncthreads();
    s = red[0] + red[1] + red[2] + red[3];
    float inv = 1.0f / s;
#pragma unroll
    for (int i = 0; i < 4; ++i) {
        int n = t + 256 * i;
        if (n < NNODES) attn[(size_t)b * NNODES + n] = sv[i] * inv;
    }
}

// ---------------------------------------------------------------------------
// context partials
// ---------------------------------------------------------------------------
__global__ void k_context(const ushort_t* __restrict__ hhi, const ushort_t* __restrict__ hlo,
                          const float* __restrict__ attn, float* __restrict__ partial)
{
    int b = blockIdx.x, ch = blockIdx.y, k = threadIdx.x;
    int n0 = ch * 128;
    int n1 = n0 + 128; if (n1 > NNODES) n1 = NNODES;
    float s = 0.f;
    for (int n = n0; n < n1; ++n) {
        size_t i = ((size_t)b * NNODES + n) * HD + k;
        s = fmaf(attn[(size_t)b * NNODES + n], rh2(hhi[i], hlo[i]), s);
    }
    partial[((size_t)b * 8 + ch) * HD + k] = s;
}

// ---------------------------------------------------------------------------
// final head
// ---------------------------------------------------------------------------
__global__ void k_final(const float* __restrict__ partial,
                        const float* __restrict__ wh_W, const float* __restrict__ wh_b,
                        const float* __restrict__ lin_W, const float* __restrict__ lin_b,
                        float* __restrict__ out)
{
    int b = blockIdx.x, j = threadIdx.x;
    __shared__ float ctx[HD];
    __shared__ float hid[HD];
    float s = 0.f;
#pragma unroll
    for (int ch = 0; ch < 8; ++ch) s += partial[((size_t)b * 8 + ch) * HD + j];
    ctx[j] = s;
    __syncthreads();
    float a = wh_b[j];
    for (int k = 0; k < HD; ++k) a = fmaf(ctx[k], wh_W[j * HD + k], a);
    hid[j] = fmaxf(a, 0.f);
    __syncthreads();
    if (j < 10) {
        float o = lin_b[j];
        for (int k = 0; k < HD; ++k) o = fmaf(hid[k], lin_W[j * HD + k], o);
        out[b * 10 + j] = o;
    }
}

// ---------------------------------------------------------------------------
extern "C" void kernel_launch(void* const* d_in, const int* in_sizes, int n_in,
                              void* d_out, int out_size, void* d_ws, size_t ws_size,
                              hipStream_t stream)
{
    const int*   wordid = (const int*)d_in[0];
    const float* c0     = (const float*)d_in[2];
    const float* emb    = (const float*)d_in[3];
    const float* W_iou  = (const float*)d_in[4];
    const float* U_iou  = (const float*)d_in[5];
    const float* b_iou  = (const float*)d_in[6];
    const float* Uf_W   = (const float*)d_in[7];
    const float* Uf_b   = (const float*)d_in[8];
    const float* Wmem   = (const float*)d_in[9];
    const float* wh_W   = (const float*)d_in[10];
    const float* wh_b   = (const float*)d_in[11];
    const float* lin_W  = (const float*)d_in[12];
    const float* lin_b  = (const float*)d_in[13];
    float* out = (float*)d_out;

    const int V = in_sizes[3] / 256;     // vocab (32000)
    const size_t nh = (size_t)BB * NNODES * HD;

    char* ws = (char*)d_ws;
    size_t off = 0;
    auto alloc = [&](size_t bytes) -> void* {
        void* p = ws + off;
        off += (bytes + 255) & ~(size_t)255;
        return p;
    };
    ushort_t* hhi  = (ushort_t*)alloc(nh * 2);
    ushort_t* hlo  = (ushort_t*)alloc(nh * 2);
    float*    c    = (float*)   alloc(nh * 4);
    ushort_t* ehi  = (ushort_t*)alloc((size_t)V * 256 * 2);
    ushort_t* elo  = (ushort_t*)alloc((size_t)V * 256 * 2);
    ushort_t* wchi = (ushort_t*)alloc((size_t)LDCOMB * 512 * 2);
    ushort_t* wclo = (ushort_t*)alloc((size_t)LDCOMB * 512 * 2);
    ushort_t* wihi = (ushort_t*)alloc((size_t)IOU3 * 256 * 2);
    ushort_t* wilo = (ushort_t*)alloc((size_t)IOU3 * 256 * 2);
    int*   ids     = (int*)  alloc((size_t)BB * LEAVES * 4);
    float* v       = (float*)alloc((size_t)BB * HD * 4);
    float* scores  = (float*)alloc((size_t)BB * NNODES * 4);
    float* attn    = (float*)alloc((size_t)BB * NNODES * 4);
    float* partial = (float*)alloc((size_t)BB * 8 * HD * 4);

    size_t remain = (ws_size > off) ? (ws_size - off) : 0;
    size_t rows = remain / (LDCOMB * 4);
    int CH = (int)((rows > 16384) ? 16384 : rows);
    CH &= ~127;
    if (CH < 128) CH = 128;
    float* buf = (float*)alloc((size_t)CH * LDCOMB * 4);

    // ---- one-time splits ----
    k_split4<<<(V * 256 / 4 + 255) / 256, 256, 0, stream>>>(emb, ehi, elo, V * 256 / 4);
    k_build_wcat<<<(1280 * 128 + 255) / 256, 256, 0, stream>>>(Uf_W, U_iou, wchi, wclo);
    k_split4<<<(IOU3 * 256 / 4 + 255) / 256, 256, 0, stream>>>(W_iou, wihi, wilo, IOU3 * 256 / 4);
    k_leaf_ids<<<(BB * LEAVES) / 256, 256, 0, stream>>>(wordid, ids);

    // ---- leaves: gather GEMM (K=256, N=768) + apply ----
    {
        int M = BB * LEAVES;
        for (int m0 = 0; m0 < M; m0 += CH) {
            int Mc = M - m0; if (Mc > CH) Mc = CH;
            dim3 g(Mc / BM, IOU3 / BN);
            gemm_mfma<<<g, 256, 0, stream>>>(ehi, elo, ids, 0, 0u, 0, m0, 256,
                                             wihi, wilo, buf, IOU3);
            k_apply_leaf<<<Mc, 256, 0, stream>>>(buf, b_iou, c0, hhi, hlo, c, m0);
        }
    }

    // ---- internal levels, deepest first: fused [Uf;U_iou] GEMM (K=512,N=1280) ----
    for (int L = 8; L >= 0; --L) {
        int npar = 1 << L;
        int ps = (1 << L) - 1;
        int cs = (1 << (L + 1)) - 1;
        int M = BB * npar;
        unsigned sB = NNODES * HD;          // batch stride in h (elements)
        int sP = 2 * HD;                    // parent stride (children contiguous)
        const ushort_t* Abh = hhi + (size_t)cs * HD;
        const ushort_t* Abl = hlo + (size_t)cs * HD;
        for (int m0 = 0; m0 < M; m0 += CH) {
            int Mc = M - m0; if (Mc > CH) Mc = CH;
            dim3 g(Mc / BM, LDCOMB / BN);
            gemm_mfma<<<g, 256, 0, stream>>>(Abh, Abl, (const int*)nullptr, L, sB, sP,
                                             m0, CAT2, wchi, wclo, buf, LDCOMB);
            k_apply_level<<<Mc, 256, 0, stream>>>(buf, b_iou, Uf_b, hhi, hlo, c,
                                                  m0, L, ps, cs);
        }
    }

    // ---- attention + head ----
    k_dec_v<<<BB, HD, 0, stream>>>(hhi, hlo, Wmem, v);
    k_scores<<<dim3(BB, 256), 256, 0, stream>>>(hhi, hlo, v, scores);
    k_softmax<<<BB, 256, 0, stream>>>(scores, attn);
    k_context<<<dim3(BB, 8), HD, 0, stream>>>(hhi, hlo, attn, partial);
    k_final<<<BB, HD, 0, stream>>>(partial, wh_W, wh_b, lin_W, lin_b, out);
}